// Round 12
// baseline (56.481 us; speedup 1.0000x reference)
//
#include <hip/hip_runtime.h>

// Problem constants (fixed shapes from setup_inputs)
constexpr int KK = 3;
constexpr int K2 = 9;          // KK*KK
constexpr int PADC = 1;        // (KK-1)/2
constexpr float DECAY = 4.0f;
constexpr float RELT = 0.3f;
constexpr float EPSV = 1e-8f;
constexpr int H = 480;
constexpr int W = 640;
constexpr int HW = H * W;

typedef float f32x4 __attribute__((ext_vector_type(4)));   // native vector: ok for nontemporal builtins

// Tiling: 16x64 tile; 256 threads x 4 px. Channel work split across TWO blocks
// per tile (center + 4 channels each) -> 2x waves, half the serial chain.
constexpr int TH = 16;
constexpr int TW = 64;
constexpr int PADT = 8;              // apron: N(0,1) offsets + kernel +-1 stay within +-8 in practice
constexpr int LR = TH + 2 * PADT;    // 32 staged rows
constexpr int LC = TW + 2 * PADT;    // 80 staged cols (valid)
constexpr int LSTRIDE = LC + 1;      // 81: odd stride de-phases LDS banks across rows
constexpr int NSTAGE = LR * LC;      // 2560 = 10 * 256 exactly

// Global-path bilinear corner fetch with zero padding (always-correct fallback).
__device__ __forceinline__ float dsample(const float* __restrict__ img, int iy, int ix) {
    bool valid = (iy >= 0) & (iy < H) & (ix >= 0) & (ix < W);
    int iyc = min(max(iy, 0), H - 1);
    int ixc = min(max(ix, 0), W - 1);
    float v = img[iyc * W + ixc];
    return valid ? v : 0.0f;
}

// One bilinear tap for 4 consecutive pixels; single fast/slow branch per tap.
__device__ __forceinline__ void tap4(const float* __restrict__ tile,
                                     const float* __restrict__ dimg,
                                     int by0, int bx0, int r, int col,
                                     f32x4 oy, f32x4 ox, int ky, int kx,
                                     float* s4) {
    int y0[4], x0[4];
    float wy[4], wx[4];
    bool fast = true;
#pragma unroll
    for (int j = 0; j < 4; ++j) {
        float pyt = oy[j] + (float)(r + PADT + ky);
        float pxt = ox[j] + (float)(col + j + PADT + kx);
        float y0f = floorf(pyt);
        float x0f = floorf(pxt);
        wy[j] = pyt - y0f;
        wx[j] = pxt - x0f;
        y0[j] = (int)y0f;
        x0[j] = (int)x0f;
        fast &= ((unsigned)y0[j] < (unsigned)(LR - 1)) & ((unsigned)x0[j] < (unsigned)(LC - 1));
    }
    if (fast) {
        // zeros for out-of-image texels are already staged in the tile
#pragma unroll
        for (int j = 0; j < 4; ++j) {
            int a = y0[j] * LSTRIDE + x0[j];
            float v00 = tile[a];
            float v01 = tile[a + 1];
            float v10 = tile[a + LSTRIDE];
            float v11 = tile[a + LSTRIDE + 1];
            float h0 = fmaf(wx[j], v01 - v00, v00);
            float h1 = fmaf(wx[j], v11 - v10, v10);
            s4[j] = fmaf(wy[j], h1 - h0, h0);
        }
    } else {
        // rare: sample outside the apron -> fully general global path
#pragma unroll
        for (int j = 0; j < 4; ++j) {
            int gy = y0[j] + by0 - PADT;
            int gx = x0[j] + bx0 - PADT;
            float v00 = dsample(dimg, gy, gx);
            float v01 = dsample(dimg, gy, gx + 1);
            float v10 = dsample(dimg, gy + 1, gx);
            float v11 = dsample(dimg, gy + 1, gx + 1);
            float h0 = fmaf(wx[j], v01 - v00, v00);
            float h1 = fmaf(wx[j], v11 - v10, v10);
            s4[j] = fmaf(wy[j], h1 - h0, h0);
        }
    }
}

__global__ __launch_bounds__(256) void affinity_kernel(
    const float* __restrict__ depth,    // [B,1,H,W]
    const float* __restrict__ offset,   // [B,2*K2,H,W]
    float* __restrict__ out)            // [B,K2,H,W]
{
    const int bx0  = blockIdx.x * TW;
    const int by0  = blockIdx.y * TH;
    const int b    = blockIdx.z >> 1;
    const int half = blockIdx.z & 1;
    const int t    = threadIdx.x;

    __shared__ float tile[LR * LSTRIDE];

    const float* __restrict__ dimg = depth + (size_t)b * HW;

    const int col = (t & 15) * 4;        // 4 consecutive x per thread (16B aligned)
    const int r   = t >> 4;              // 0..15
    const int y   = by0 + r;
    const int x   = bx0 + col;

    const size_t obase = ((size_t)b * 2 * K2) * HW + (size_t)y * W + x;
    const float* __restrict__ offp = offset + obase;

    // Each half does: center (for thresholds) + 4 channels.
    // half 0 -> {4, 0, 1, 2, 3}; half 1 -> {4, 5, 6, 7, 8}
    constexpr int NCH = 5;
    const int chbase = half ? 5 : 0;     // ORD[i] = (i==0) ? 4 : chbase + i - 1
#define ORD(i) ((i) == 0 ? 4 : chbase + (i) - 1)

    // Issue the first channel's loads before staging: latency hides under staging+barrier.
    f32x4 oyc = *reinterpret_cast<const f32x4*>(offp + (size_t)(2 * 4) * HW);
    f32x4 oxc = *reinterpret_cast<const f32x4*>(offp + (size_t)(2 * 4 + 1) * HW);

    // Stage depth apron into LDS with zero padding baked in (coalesced, exact fit).
#pragma unroll
    for (int i = 0; i < NSTAGE / 256; ++i) {
        int idx = t + i * 256;
        int rr = idx / LC;               // constant divisor
        int cc = idx - rr * LC;
        int yi = by0 - PADT + rr;
        int xi = bx0 - PADT + cc;
        float v = 0.0f;
        if ((unsigned)yi < (unsigned)H && (unsigned)xi < (unsigned)W)
            v = dimg[yi * W + xi];
        tile[rr * LSTRIDE + cc] = v;
    }
    __syncthreads();

    float* __restrict__ outp = out + ((size_t)b * K2) * HW + (size_t)y * W + x;

    float c4[4], thr[4], cr[4];

    // Rolling 1-deep prefetch: issue k+1's offset loads before computing k.
#pragma unroll
    for (int i = 0; i < NCH; ++i) {
        const int k = ORD(i);
        f32x4 oyn, oxn;
        if (i + 1 < NCH) {
            const int kn = ORD(i + 1);
            oyn = *reinterpret_cast<const f32x4*>(offp + (size_t)(2 * kn) * HW);
            oxn = *reinterpret_cast<const f32x4*>(offp + (size_t)(2 * kn + 1) * HW);
        }

        float s4[4];
        tap4(tile, dimg, by0, bx0, r, col, oyc, oxc, k / KK - PADC, k % KK - PADC, s4);

        if (i == 0) {
            // center channel: defines thresholds; its own output is identically 1.0
#pragma unroll
            for (int j = 0; j < 4; ++j) {
                c4[j]  = s4[j];
                thr[j] = RELT * (s4[j] + EPSV);  // diff/(c+eps)<=0.3 <=> diff<=0.3*(c+eps), c>=0
                cr[j]  = RELT * s4[j];
            }
            if (half == 0) {
                f32x4 ones = {1.0f, 1.0f, 1.0f, 1.0f};
                __builtin_nontemporal_store(ones, reinterpret_cast<f32x4*>(outp + (size_t)4 * HW));
            }
        } else {
            f32x4 vals;
#pragma unroll
            for (int j = 0; j < 4; ++j) {
                float diff = fabsf(s4[j] - c4[j]);
                float aff = __expf(-DECAY * (diff - cr[j]));
                vals[j] = (diff <= thr[j]) ? 1.0f : aff;
            }
            __builtin_nontemporal_store(vals, reinterpret_cast<f32x4*>(outp + (size_t)k * HW));
        }
        oyc = oyn;
        oxc = oxn;
    }
#undef ORD
}

extern "C" void kernel_launch(void* const* d_in, const int* in_sizes, int n_in,
                              void* d_out, int out_size, void* d_ws, size_t ws_size,
                              hipStream_t stream) {
    const float* depth = (const float*)d_in[0];
    const float* offset = (const float*)d_in[1];
    float* out = (float*)d_out;

    int B = in_sizes[0] / HW;          // depth is [B,1,H,W]
    dim3 grid(W / TW, H / TH, 2 * B);  // 10 x 30 x 16: two channel-halves per tile
    affinity_kernel<<<grid, 256, 0, stream>>>(depth, offset, out);
}

// Round 13
// 50.313 us; speedup vs baseline: 1.1226x; 1.1226x over previous
//
#include <hip/hip_runtime.h>

// Problem constants (fixed shapes from setup_inputs)
constexpr int KK = 3;
constexpr int K2 = 9;          // KK*KK
constexpr int PADC = 1;        // (KK-1)/2
constexpr float DECAY = 4.0f;
constexpr float RELT = 0.3f;
constexpr float EPSV = 1e-8f;
constexpr int H = 480;
constexpr int W = 640;
constexpr int HW = H * W;

typedef float f32x2 __attribute__((ext_vector_type(2)));
typedef float f32x4 __attribute__((ext_vector_type(4)));   // native vectors: ok for nontemporal builtins

// Tiling: each block produces a 16x64 tile; 256 threads x 4 px (f32x4 I/O).
constexpr int TH = 16;
constexpr int TW = 64;
constexpr int PADT = 8;              // apron: N(0,1) offsets + kernel +-1 stay within +-8 in practice
constexpr int LR = TH + 2 * PADT;    // 32 staged rows
constexpr int LC = TW + 2 * PADT;    // 80 staged cols (valid)

// f32 pair-plane LDS tile: plane p, row y, pair i holds (tex[y][2i+p], tex[y][2i+p+1]).
// A bilinear tap = 2 aligned ds_read_b64 (one per row), selected by x0 parity.
constexpr int NPAIR = 42;            // pairs per row incl pad -> 336B row stride (16B-aligned)
constexpr int PLANE = LR * NPAIR;    // 1344 pairs per plane; LDS total 2*1344*8 = 21504 B
constexpr int NCHUNK = LR * (LC / 4);  // 640 4-col staging chunks

// Global-path bilinear corner fetch with zero padding (always-correct fallback).
__device__ __forceinline__ float dsample(const float* __restrict__ img, int iy, int ix) {
    bool valid = (iy >= 0) & (iy < H) & (ix >= 0) & (ix < W);
    int iyc = min(max(iy, 0), H - 1);
    int ixc = min(max(ix, 0), W - 1);
    float v = img[iyc * W + ixc];
    return valid ? v : 0.0f;
}

// One bilinear tap for 4 consecutive pixels; single fast/slow branch per tap.
__device__ __forceinline__ void tap4(const f32x2* __restrict__ tile,
                                     const float* __restrict__ dimg,
                                     int by0, int bx0, int r, int col,
                                     f32x4 oy, f32x4 ox, int ky, int kx,
                                     float* s4) {
    int y0[4], x0[4];
    float wy[4], wx[4];
    bool fast = true;
#pragma unroll
    for (int j = 0; j < 4; ++j) {
        float pyt = oy[j] + (float)(r + PADT + ky);
        float pxt = ox[j] + (float)(col + j + PADT + kx);
        float y0f = floorf(pyt);
        float x0f = floorf(pxt);
        wy[j] = pyt - y0f;
        wx[j] = pxt - x0f;
        y0[j] = (int)y0f;
        x0[j] = (int)x0f;
        fast &= ((unsigned)y0[j] < (unsigned)(LR - 1)) & ((unsigned)x0[j] < (unsigned)(LC - 1));
    }
    if (fast) {
        // zeros for out-of-image texels are already staged in the tile
#pragma unroll
        for (int j = 0; j < 4; ++j) {
            int p = x0[j] & 1;
            int a = p * PLANE + y0[j] * NPAIR + (x0[j] >> 1);
            f32x2 top = tile[a];             // (v00, v01)
            f32x2 bot = tile[a + NPAIR];     // (v10, v11)
            float h0 = fmaf(wx[j], top.y - top.x, top.x);
            float h1 = fmaf(wx[j], bot.y - bot.x, bot.x);
            s4[j] = fmaf(wy[j], h1 - h0, h0);
        }
    } else {
        // rare: sample outside the apron -> fully general global path
#pragma unroll
        for (int j = 0; j < 4; ++j) {
            int gy = y0[j] + by0 - PADT;
            int gx = x0[j] + bx0 - PADT;
            float v00 = dsample(dimg, gy, gx);
            float v01 = dsample(dimg, gy, gx + 1);
            float v10 = dsample(dimg, gy + 1, gx);
            float v11 = dsample(dimg, gy + 1, gx + 1);
            float h0 = fmaf(wx[j], v01 - v00, v00);
            float h1 = fmaf(wx[j], v11 - v10, v10);
            s4[j] = fmaf(wy[j], h1 - h0, h0);
        }
    }
}

__global__ __launch_bounds__(256) void affinity_kernel(
    const float* __restrict__ depth,    // [B,1,H,W]
    const float* __restrict__ offset,   // [B,2*K2,H,W]
    float* __restrict__ out)            // [B,K2,H,W]
{
    const int bx0 = blockIdx.x * TW;
    const int by0 = blockIdx.y * TH;
    const int b   = blockIdx.z;
    const int t   = threadIdx.x;

    __shared__ f32x2 tile[2 * PLANE];

    const float* __restrict__ dimg = depth + (size_t)b * HW;

    const int col = (t & 15) * 4;        // 4 consecutive x per thread (16B aligned)
    const int r   = t >> 4;              // 0..15
    const int y   = by0 + r;
    const int x   = bx0 + col;

    const size_t obase = ((size_t)b * 2 * K2) * HW + (size_t)y * W + x;
    const float* __restrict__ offp = offset + obase;

    // Channel order: center (k=4) first so thresholds are ready before the rest.
    constexpr int ORD[K2] = {4, 0, 1, 2, 3, 5, 6, 7, 8};

    // Issue the first channel's loads before staging: latency hides under staging+barrier.
    f32x4 oyc = *reinterpret_cast<const f32x4*>(offp + (size_t)(2 * ORD[0]) * HW);
    f32x4 oxc = *reinterpret_cast<const f32x4*>(offp + (size_t)(2 * ORD[0] + 1) * HW);

    // Stage the depth apron as f32 pair-planes. Each 4-col chunk (c0 = 4*cx)
    // writes plane0 pairs (v0,v1),(v2,v3) and plane1 pairs (v1,v2),(v3,v4)
    // as two aligned 16B LDS writes. Interior blocks: one f32x4 + one scalar
    // global load per chunk; border blocks: clamped scalar path (zero-padded).
    const bool interior = (by0 >= PADT) && (by0 + TH + PADT <= H) &&
                          (bx0 >= PADT) && (bx0 + (LC - PADT) + 4 <= W);
#pragma unroll
    for (int i = 0; i < 3; ++i) {
        int idx = t + i * 256;
        if (idx < NCHUNK) {
            int rr = idx / (LC / 4);         // constant divisor (20 chunks/row)
            int cx = idx - rr * (LC / 4);
            int c0 = cx * 4;
            f32x4 v;
            float v4;
            if (interior) {
                const float* rowp = dimg + (size_t)(by0 - PADT + rr) * W + (bx0 - PADT);
                v  = *reinterpret_cast<const f32x4*>(rowp + c0);   // 16B aligned
                v4 = rowp[c0 + 4];
            } else {
                int gy = by0 - PADT + rr;
                bool yok = (unsigned)gy < (unsigned)H;
                const float* rowp = dimg + (size_t)min(max(gy, 0), H - 1) * W;
                float e[5];
#pragma unroll
                for (int jj = 0; jj < 5; ++jj) {
                    int gx = bx0 - PADT + c0 + jj;
                    bool ok = yok & ((unsigned)gx < (unsigned)W);
                    e[jj] = ok ? rowp[min(max(gx, 0), W - 1)] : 0.0f;
                }
                v = f32x4{e[0], e[1], e[2], e[3]};
                v4 = e[4];
            }
            int pbase = rr * NPAIR + (c0 >> 1);   // even pair index -> 16B aligned
            f32x4 p0 = {v.x, v.y, v.z, v.w};
            f32x4 p1 = {v.y, v.z, v.w, v4};
            *reinterpret_cast<f32x4*>(&tile[pbase]) = p0;
            *reinterpret_cast<f32x4*>(&tile[PLANE + pbase]) = p1;
        }
    }
    __syncthreads();

    float* __restrict__ outp = out + ((size_t)b * K2) * HW + (size_t)y * W + x;

    float c4[4], thr[4], cr[4];

    // Rolling 1-deep prefetch: issue k+1's offset loads before computing k.
#pragma unroll
    for (int i = 0; i < K2; ++i) {
        const int k = ORD[i];
        f32x4 oyn, oxn;
        if (i + 1 < K2) {
            oyn = *reinterpret_cast<const f32x4*>(offp + (size_t)(2 * ORD[i + 1]) * HW);
            oxn = *reinterpret_cast<const f32x4*>(offp + (size_t)(2 * ORD[i + 1] + 1) * HW);
        }

        float s4[4];
        tap4(tile, dimg, by0, bx0, r, col, oyc, oxc, k / KK - PADC, k % KK - PADC, s4);

        if (i == 0) {
            // center channel: defines thresholds; its own output is identically 1.0
#pragma unroll
            for (int j = 0; j < 4; ++j) {
                c4[j]  = s4[j];
                thr[j] = RELT * (s4[j] + EPSV);  // diff/(c+eps)<=0.3 <=> diff<=0.3*(c+eps), c>=0
                cr[j]  = RELT * s4[j];
            }
            f32x4 ones = {1.0f, 1.0f, 1.0f, 1.0f};
            __builtin_nontemporal_store(ones, reinterpret_cast<f32x4*>(outp + (size_t)4 * HW));
        } else {
            f32x4 vals;
#pragma unroll
            for (int j = 0; j < 4; ++j) {
                float diff = fabsf(s4[j] - c4[j]);
                float aff = __expf(-DECAY * (diff - cr[j]));
                vals[j] = (diff <= thr[j]) ? 1.0f : aff;
            }
            __builtin_nontemporal_store(vals, reinterpret_cast<f32x4*>(outp + (size_t)k * HW));
        }
        oyc = oyn;
        oxc = oxn;
    }
}

extern "C" void kernel_launch(void* const* d_in, const int* in_sizes, int n_in,
                              void* d_out, int out_size, void* d_ws, size_t ws_size,
                              hipStream_t stream) {
    const float* depth = (const float*)d_in[0];
    const float* offset = (const float*)d_in[1];
    float* out = (float*)d_out;

    int B = in_sizes[0] / HW;          // depth is [B,1,H,W]
    dim3 grid(W / TW, H / TH, B);      // 10 x 30 x B
    affinity_kernel<<<grid, 256, 0, stream>>>(depth, offset, out);
}